// Round 2
// baseline (98.307 us; speedup 1.0000x reference)
//
#include <hip/hip_runtime.h>
#include <math.h>

// Problem constants (match reference setup_inputs)
#define BB 4
#define NN 16384
#define MM 2048
#define BM (BB*MM)      // 8192  (sample queries)
#define BN (BB*NN)      // 65536 (xyz queries)

#define TGT 1024        // targets per k_min block (staged once in LDS, 16 KB)
#define QPB 512         // queries per k_min block (2 per thread)
#define S1  16          // target splits for dir1 (smp->xyz): 16*1024 = N
#define S2  2           // target splits for dir2 (xyz->smp): 2*1024  = M

// Workspace layout (floats). No initialization needed anywhere: every slot is
// plain-stored by exactly one owner before being read.
#define PART1OFF 0                       // [S1*BM]  dir1 partial mins (+qsq)
#define PART2OFF (S1*BM)                 // [S2*BN]  dir2 partial mins (+qsq)
#define REDOFF   (PART1OFF + S1*BM + S2*BN)
#define R_SUMS1  (REDOFF)                // [8]  per-block sums of d_smp_org
#define R_MAXES  (REDOFF+8)              // [8]  per-block maxes of d_smp_org
#define R_SUMS2  (REDOFF+16)             // [64] per-block sums of d_org_smp
#define R_GST    (REDOFF+80)             // [32] trans partial sums
#define R_GSR    (REDOFF+112)            // [32] rot partial sums
#define R_GSC    (REDOFF+144)            // [32] cls partial sums

// 512 blocks. Each owns 512 queries x 1024 targets; writes one partial-min
// per query (plain store). Per-target LDS float4 = (-2x,-2y,-2z, |p|^2);
// d' = fma chain; true d = d' + |q|^2 added at the end.
__global__ __launch_bounds__(256) void k_min(const float* __restrict__ xyz,
                                             const float* __restrict__ smp,
                                             float* __restrict__ ws) {
    __shared__ float4 tgt[TGT];
    const int tid = threadIdx.x;
    const int bx  = blockIdx.x;
    const float* qptr; const float* tptr; float* outp;
    if (bx < 256) {
        // dir2: queries = xyz (BN), targets = smp. 128 query-blocks x 2 splits.
        int qb = bx >> 1, s = bx & 1;
        int gq = qb * QPB;                 // global query index in [0, BN)
        int b  = gq >> 14;                 // batch = gq / NN
        qptr = xyz + (size_t)gq * 3;
        tptr = smp + (size_t)(b * MM + s * TGT) * 3;
        outp = ws + PART2OFF + s * BN + gq;
    } else {
        // dir1: queries = smp (BM), targets = xyz. 16 query-blocks x 16 splits.
        int bx2 = bx - 256;
        int qb = bx2 >> 4, s = bx2 & 15;
        int gq = qb * QPB;                 // global query index in [0, BM)
        int b  = gq >> 11;                 // batch = gq / MM
        qptr = smp + (size_t)gq * 3;
        tptr = xyz + (size_t)(b * NN + s * TGT) * 3;
        outp = ws + PART1OFF + s * BM + gq;
    }
    for (int p = tid; p < TGT; p += 256) {
        float x = tptr[3*p], y = tptr[3*p+1], z = tptr[3*p+2];
        tgt[p] = make_float4(-2.0f*x, -2.0f*y, -2.0f*z, x*x + y*y + z*z);
    }
    float qx0 = qptr[3*tid],       qy0 = qptr[3*tid+1],       qz0 = qptr[3*tid+2];
    float qx1 = qptr[3*(tid+256)], qy1 = qptr[3*(tid+256)+1], qz1 = qptr[3*(tid+256)+2];
    float mn0 = INFINITY, mn1 = INFINITY;
    __syncthreads();
#pragma unroll 4
    for (int j = 0; j < TGT; j += 2) {
        float4 ta = tgt[j], tb = tgt[j+1];
        float d0a = fmaf(ta.x, qx0, fmaf(ta.y, qy0, fmaf(ta.z, qz0, ta.w)));
        float d0b = fmaf(tb.x, qx0, fmaf(tb.y, qy0, fmaf(tb.z, qz0, tb.w)));
        mn0 = fminf(mn0, fminf(d0a, d0b));            // -> v_min3_f32
        float d1a = fmaf(ta.x, qx1, fmaf(ta.y, qy1, fmaf(ta.z, qz1, ta.w)));
        float d1b = fmaf(tb.x, qx1, fmaf(tb.y, qy1, fmaf(tb.z, qz1, tb.w)));
        mn1 = fminf(mn1, fminf(d1a, d1b));
    }
    outp[tid]       = mn0 + (qx0*qx0 + qy0*qy0 + qz0*qz0);
    outp[tid + 256] = mn1 + (qx1*qx1 + qy1*qy1 + qz1*qz1);
}

__device__ __forceinline__ float blockSum256(float v, volatile float* s4) {
#pragma unroll
    for (int o = 32; o > 0; o >>= 1) v += __shfl_down(v, o, 64);
    __syncthreads();                       // safe reuse of s4
    int lane = threadIdx.x & 63, w = threadIdx.x >> 6;
    if (lane == 0) s4[w] = v;
    __syncthreads();
    return s4[0] + s4[1] + s4[2] + s4[3];
}

__device__ __forceinline__ float blockMax256(float v, volatile float* s4) {
#pragma unroll
    for (int o = 32; o > 0; o >>= 1) v = fmaxf(v, __shfl_down(v, o, 64));
    __syncthreads();
    int lane = threadIdx.x & 63, w = threadIdx.x >> 6;
    if (lane == 0) s4[w] = v;
    __syncthreads();
    return fmaxf(fmaxf(s4[0], s4[1]), fmaxf(s4[2], s4[3]));
}

// 104 blocks: [0,8) dir1 min-combine + sum + max; [8,72) dir2 min-combine + sum;
// [72,104) grasp/cls terms. All outputs are plain per-block stores.
__global__ __launch_bounds__(256) void k_reduce(const float* __restrict__ gp,
                                                const float* __restrict__ gg,
                                                const float* __restrict__ cp,
                                                const float* __restrict__ cg,
                                                float* __restrict__ ws) {
    __shared__ float s4a[4], s4b[4], s4c[4];
    const int bx = blockIdx.x, tid = threadIdx.x;
    if (bx < 8) {
        float s = 0.0f, mx = -INFINITY;
#pragma unroll
        for (int k = 0; k < 4; ++k) {
            int q = bx * 1024 + tid + k * 256;
            float v = INFINITY;
#pragma unroll
            for (int sp = 0; sp < S1; ++sp) v = fminf(v, ws[PART1OFF + sp * BM + q]);
            s += v; mx = fmaxf(mx, v);
        }
        float bs = blockSum256(s, s4a);
        float bm = blockMax256(mx, s4b);
        if (tid == 0) { ws[R_SUMS1 + bx] = bs; ws[R_MAXES + bx] = bm; }
    } else if (bx < 72) {
        int i = bx - 8;
        float s = 0.0f;
#pragma unroll
        for (int k = 0; k < 4; ++k) {
            int q = i * 1024 + tid + k * 256;
            s += fminf(ws[PART2OFF + q], ws[PART2OFF + BN + q]);
        }
        float bs = blockSum256(s, s4a);
        if (tid == 0) ws[R_SUMS2 + i] = bs;
    } else {
        int m = (bx - 72) * 256 + tid;            // [0, 8192)
        const float* g = gp + (size_t)m * 7;
        float cxp = g[0], cyp = g[1], czp = g[2];
        float q0 = g[3], q1 = g[4], q2 = g[5], q3 = g[6];
        float invq = 1.0f / sqrtf(q0*q0 + q1*q1 + q2*q2 + q3*q3 + 1e-12f);
        const float* G = gg + (size_t)m * 16;
        float tr = G[0] + G[5] + G[10];
        float w = 0.5f * sqrtf(fmaxf(1.0f + tr, 1e-12f));
        float inv4w = 1.0f / (4.0f * w);
        float gqx = (G[9] - G[6]) * inv4w;
        float gqy = (G[2] - G[8]) * inv4w;
        float gqz = (G[4] - G[1]) * inv4w;
        float cw = cg[m];
        float dx = cxp - G[3]  + 1e-6f;
        float dy = cyp - G[7]  + 1e-6f;
        float dz = czp - G[11] + 1e-6f;
        float dist = sqrtf(dx*dx + dy*dy + dz*dz);
        float dot = (q0*w + q1*gqx + q2*gqy + q3*gqz) * invq;
        float rot = acosf(fminf(fabsf(dot), 1.0f - 1e-7f));
        float p = fminf(fmaxf(cp[m], 1e-7f), 1.0f - 1e-7f);
        float ce = cw * logf(p) + (1.0f - cw) * logf(1.0f - p);
        float s1 = blockSum256(dist * cw, s4a);
        float s2 = blockSum256(rot  * cw, s4b);
        float s3 = blockSum256(ce, s4c);
        int i = bx - 72;
        if (tid == 0) { ws[R_GST + i] = s1; ws[R_GSR + i] = s2; ws[R_GSC + i] = s3; }
    }
}

// GAMMA=0.5 ALPHA=0.5 BETA=1 THETA=1
__global__ __launch_bounds__(256) void k_final(const float* __restrict__ temp,
                                               const float* __restrict__ ws,
                                               float* __restrict__ out) {
    __shared__ float s4[4];
    const int tid = threadIdx.x;
    float a = (tid < 8)  ? ws[R_SUMS1 + tid] : 0.0f;
    float f = (tid < 4)  ? fmaxf(ws[R_MAXES + 2*tid], ws[R_MAXES + 2*tid + 1]) : 0.0f;
    float b = (tid < 64) ? ws[R_SUMS2 + tid] : 0.0f;
    float c = (tid < 32) ? ws[R_GST + tid] : 0.0f;
    float d = (tid < 32) ? ws[R_GSR + tid] : 0.0f;
    float e = (tid < 32) ? ws[R_GSC + tid] : 0.0f;
    float A = blockSum256(a, s4);
    float F = blockSum256(f, s4);
    float B = blockSum256(b, s4);
    float C = blockSum256(c, s4);
    float D = blockSum256(d, s4);
    float E = blockSum256(e, s4);
    if (tid == 0) {
        float sample = A * (1.0f / BM) + F * 0.25f + 0.5f * B * (1.0f / BN);
        float reg    = C * (1.0f / BM) + 0.5f * D * (1.0f / BM);
        float cls    = -E * (1.0f / BM);
        float t = temp[0];
        out[0] = sample + t * t + reg + cls;
    }
}

extern "C" void kernel_launch(void* const* d_in, const int* in_sizes, int n_in,
                              void* d_out, int out_size, void* d_ws, size_t ws_size,
                              hipStream_t stream) {
    const float* xyz  = (const float*)d_in[0];
    const float* smp  = (const float*)d_in[1];
    const float* temp = (const float*)d_in[2];
    const float* gp   = (const float*)d_in[3];
    const float* gg   = (const float*)d_in[4];
    const float* cp   = (const float*)d_in[5];
    const float* cg   = (const float*)d_in[6];
    float* ws  = (float*)d_ws;
    float* out = (float*)d_out;

    hipLaunchKernelGGL(k_min,    dim3(512), dim3(256), 0, stream, xyz, smp, ws);
    hipLaunchKernelGGL(k_reduce, dim3(104), dim3(256), 0, stream, gp, gg, cp, cg, ws);
    hipLaunchKernelGGL(k_final,  dim3(1),   dim3(256), 0, stream, temp, ws, out);
}

// Round 3
// 96.331 us; speedup vs baseline: 1.0205x; 1.0205x over previous
//
#include <hip/hip_runtime.h>
#include <math.h>

// Problem constants (match reference setup_inputs)
#define BB 4
#define NN 16384
#define MM 2048
#define BM (BB*MM)      // 8192  (sample queries)
#define BN (BB*NN)      // 65536 (xyz queries)

#define TGT 256         // targets per k_min block (1 KB staged -> 4 KB float4 LDS)
#define S1  64          // dir1 (smp->xyz) target splits: 64*256 = NN
#define S2  8           // dir2 (xyz->smp) target splits: 8*256  = MM

// Workspace layout (floats). Every slot plain-stored by exactly one owner
// before being read -> no init kernel, no atomics.
#define PART1OFF 0                       // [S1*BM] dir1 partial mins (incl qsq)
#define PART2OFF (S1*BM)                 // [S2*BN] dir2 partial mins (incl qsq)
#define REDOFF   (PART1OFF + S1*BM + S2*BN)
#define R_SUMS1  (REDOFF)                // [32] per-block sums of d_smp_org
#define R_MAXES  (REDOFF+32)             // [32] per-block maxes (8 blocks/batch)
#define R_SUMS2  (REDOFF+64)             // [64] per-block sums of d_org_smp
#define R_GST    (REDOFF+128)            // [32] trans partial sums
#define R_GSR    (REDOFF+160)            // [32] rot partial sums
#define R_GSC    (REDOFF+192)            // [32] cls partial sums

// 512 blocks, each: 2048 queries (8/thread) x 256 targets in LDS.
// 8 q/thread => each broadcast ds_read_b128 feeds 56 VALU ops: VALU-bound,
// not LDS-return-bound (the R1/R2 limiter at 2-4 q/thread).
// Per-target LDS float4 = (-2x,-2y,-2z,|p|^2); d' = fma chain; +|q|^2 at end.
__global__ __launch_bounds__(256) void k_min(const float* __restrict__ xyz,
                                             const float* __restrict__ smp,
                                             float* __restrict__ ws) {
    __shared__ float4 tgt[TGT];
    const int tid = threadIdx.x;
    const int bx  = blockIdx.x;
    const float* qptr; const float* tptr; float* outp;
    if (bx < 256) {
        // dir2: queries = xyz. per batch: 8 query-blocks x 8 target-splits.
        int b = bx >> 6, r = bx & 63, qb = r >> 3, s = r & 7;
        int gq = b * NN + qb * 2048;
        qptr = xyz + (size_t)gq * 3;
        tptr = smp + (size_t)(b * MM + s * TGT) * 3;
        outp = ws + PART2OFF + s * BN + gq;
    } else {
        // dir1: queries = smp. per batch: 1 query-block (2048=MM) x 64 splits.
        int bx2 = bx - 256;
        int b = bx2 >> 6, s = bx2 & 63;
        int gq = b * MM;
        qptr = smp + (size_t)gq * 3;
        tptr = xyz + (size_t)(b * NN + s * TGT) * 3;
        outp = ws + PART1OFF + s * BM + gq;
    }
    {   // stage: exactly one target per thread
        float x = tptr[3*tid], y = tptr[3*tid+1], z = tptr[3*tid+2];
        tgt[tid] = make_float4(-2.0f*x, -2.0f*y, -2.0f*z, x*x + y*y + z*z);
    }
    float qx[8], qy[8], qz[8], mn[8];
#pragma unroll
    for (int k = 0; k < 8; ++k) {
        int q = tid + k * 256;
        qx[k] = qptr[3*q]; qy[k] = qptr[3*q+1]; qz[k] = qptr[3*q+2];
        mn[k] = INFINITY;
    }
    __syncthreads();
#pragma unroll 2
    for (int j = 0; j < TGT; j += 2) {
        float4 ta = tgt[j], tb = tgt[j+1];
#pragma unroll
        for (int k = 0; k < 8; ++k) {
            float da = fmaf(ta.x, qx[k], fmaf(ta.y, qy[k], fmaf(ta.z, qz[k], ta.w)));
            float db = fmaf(tb.x, qx[k], fmaf(tb.y, qy[k], fmaf(tb.z, qz[k], tb.w)));
            mn[k] = fminf(mn[k], fminf(da, db));     // -> v_min3_f32
        }
    }
#pragma unroll
    for (int k = 0; k < 8; ++k) {
        int q = tid + k * 256;
        outp[q] = mn[k] + (qx[k]*qx[k] + qy[k]*qy[k] + qz[k]*qz[k]);
    }
}

__device__ __forceinline__ float blockSum256(float v, volatile float* s4) {
#pragma unroll
    for (int o = 32; o > 0; o >>= 1) v += __shfl_down(v, o, 64);
    __syncthreads();
    int lane = threadIdx.x & 63, w = threadIdx.x >> 6;
    if (lane == 0) s4[w] = v;
    __syncthreads();
    return s4[0] + s4[1] + s4[2] + s4[3];
}

__device__ __forceinline__ float blockMax256(float v, volatile float* s4) {
#pragma unroll
    for (int o = 32; o > 0; o >>= 1) v = fmaxf(v, __shfl_down(v, o, 64));
    __syncthreads();
    int lane = threadIdx.x & 63, w = threadIdx.x >> 6;
    if (lane == 0) s4[w] = v;
    __syncthreads();
    return fmaxf(fmaxf(s4[0], s4[1]), fmaxf(s4[2], s4[3]));
}

// 128 blocks: [0,32) dir1 combine (1 q/thread, min over 64 splits) + sum + max;
// [32,96) dir2 combine (4 q/thread, min over 8 splits) + sum;
// [96,128) grasp/cls terms. All outputs plain per-block stores.
__global__ __launch_bounds__(256) void k_reduce(const float* __restrict__ gp,
                                                const float* __restrict__ gg,
                                                const float* __restrict__ cp,
                                                const float* __restrict__ cg,
                                                float* __restrict__ ws) {
    __shared__ float s4a[4], s4b[4], s4c[4];
    const int bx = blockIdx.x, tid = threadIdx.x;
    if (bx < 32) {
        int q = bx * 256 + tid;
        float v = INFINITY;
#pragma unroll
        for (int sp = 0; sp < S1; ++sp) v = fminf(v, ws[PART1OFF + sp * BM + q]);
        float bs = blockSum256(v, s4a);
        float bm = blockMax256(v, s4b);
        if (tid == 0) { ws[R_SUMS1 + bx] = bs; ws[R_MAXES + bx] = bm; }
    } else if (bx < 96) {
        int i = bx - 32;
        float s = 0.0f;
#pragma unroll
        for (int k = 0; k < 4; ++k) {
            int q = i * 1024 + tid + k * 256;
            float v = INFINITY;
#pragma unroll
            for (int sp = 0; sp < S2; ++sp) v = fminf(v, ws[PART2OFF + sp * BN + q]);
            s += v;
        }
        float bs = blockSum256(s, s4a);
        if (tid == 0) ws[R_SUMS2 + i] = bs;
    } else {
        int m = (bx - 96) * 256 + tid;            // [0, 8192)
        const float* g = gp + (size_t)m * 7;
        float cxp = g[0], cyp = g[1], czp = g[2];
        float q0 = g[3], q1 = g[4], q2 = g[5], q3 = g[6];
        float invq = 1.0f / sqrtf(q0*q0 + q1*q1 + q2*q2 + q3*q3 + 1e-12f);
        const float* G = gg + (size_t)m * 16;
        float tr = G[0] + G[5] + G[10];
        float w = 0.5f * sqrtf(fmaxf(1.0f + tr, 1e-12f));
        float inv4w = 1.0f / (4.0f * w);
        float gqx = (G[9] - G[6]) * inv4w;
        float gqy = (G[2] - G[8]) * inv4w;
        float gqz = (G[4] - G[1]) * inv4w;
        float cw = cg[m];
        float dx = cxp - G[3]  + 1e-6f;
        float dy = cyp - G[7]  + 1e-6f;
        float dz = czp - G[11] + 1e-6f;
        float dist = sqrtf(dx*dx + dy*dy + dz*dz);
        float dot = (q0*w + q1*gqx + q2*gqy + q3*gqz) * invq;
        float rot = acosf(fminf(fabsf(dot), 1.0f - 1e-7f));
        float p = fminf(fmaxf(cp[m], 1e-7f), 1.0f - 1e-7f);
        float ce = cw * logf(p) + (1.0f - cw) * logf(1.0f - p);
        float s1 = blockSum256(dist * cw, s4a);
        float s2 = blockSum256(rot  * cw, s4b);
        float s3 = blockSum256(ce, s4c);
        int i = bx - 96;
        if (tid == 0) { ws[R_GST + i] = s1; ws[R_GSR + i] = s2; ws[R_GSC + i] = s3; }
    }
}

// GAMMA=0.5 ALPHA=0.5 BETA=1 THETA=1
__global__ __launch_bounds__(256) void k_final(const float* __restrict__ temp,
                                               const float* __restrict__ ws,
                                               float* __restrict__ out) {
    __shared__ float s4[4];
    const int tid = threadIdx.x;
    float a = (tid < 32) ? ws[R_SUMS1 + tid] : 0.0f;
    float f = 0.0f;
    if (tid < 4) {                         // per-batch max over its 8 block-maxes
        f = -INFINITY;
#pragma unroll
        for (int r = 0; r < 8; ++r) f = fmaxf(f, ws[R_MAXES + tid * 8 + r]);
    }
    float b = (tid < 64) ? ws[R_SUMS2 + tid] : 0.0f;
    float c = (tid < 32) ? ws[R_GST + tid] : 0.0f;
    float d = (tid < 32) ? ws[R_GSR + tid] : 0.0f;
    float e = (tid < 32) ? ws[R_GSC + tid] : 0.0f;
    float A = blockSum256(a, s4);
    float F = blockSum256(f, s4);
    float B = blockSum256(b, s4);
    float C = blockSum256(c, s4);
    float D = blockSum256(d, s4);
    float E = blockSum256(e, s4);
    if (tid == 0) {
        float sample = A * (1.0f / BM) + F * 0.25f + 0.5f * B * (1.0f / BN);
        float reg    = C * (1.0f / BM) + 0.5f * D * (1.0f / BM);
        float cls    = -E * (1.0f / BM);
        float t = temp[0];
        out[0] = sample + t * t + reg + cls;
    }
}

extern "C" void kernel_launch(void* const* d_in, const int* in_sizes, int n_in,
                              void* d_out, int out_size, void* d_ws, size_t ws_size,
                              hipStream_t stream) {
    const float* xyz  = (const float*)d_in[0];
    const float* smp  = (const float*)d_in[1];
    const float* temp = (const float*)d_in[2];
    const float* gp   = (const float*)d_in[3];
    const float* gg   = (const float*)d_in[4];
    const float* cp   = (const float*)d_in[5];
    const float* cg   = (const float*)d_in[6];
    float* ws  = (float*)d_ws;
    float* out = (float*)d_out;

    hipLaunchKernelGGL(k_min,    dim3(512), dim3(256), 0, stream, xyz, smp, ws);
    hipLaunchKernelGGL(k_reduce, dim3(128), dim3(256), 0, stream, gp, gg, cp, cg, ws);
    hipLaunchKernelGGL(k_final,  dim3(1),   dim3(256), 0, stream, temp, ws, out);
}